// Round 3
// baseline (269.664 us; speedup 1.0000x reference)
//
#include <hip/hip_runtime.h>

#define B_   4
#define N_   96
#define DIM_ 128
#define PB   (N_*N_)            // 9216 positions per batch
#define NPOS (B_*PB)            // 36864

// workspace layout (float offsets)
#define OFF_WEFF 0              // [24][128]  effective edge weights (t-major)
#define OFF_CALL 3072           // [24]       combined biases (be@W456, +bt for Z)
#define OFF_TN   3104           // [384][24]  node projections ti/tj/tk (+bn terms)
#define OFF_X    12320          // [4][8][96][96]  X[b][s][i][k] = e_ik + tk
#define OFF_Y    307232         // [4][8][96][96]  Y[b][s][j][k] = e_kj^T
#define OFF_Z    602144         // [4][8][96][96]  Z[b][s][i][j] = e_ij+ti+tj+bt
#define OFF_T    897056         // [4][8][96][96]  T[b][s][i][j] = max_k relu(...)

// ---------------------------------------------------------------------------
// MEASUREMENT ROUND: kernels are byte-identical to round 2. kernel_launch
// replays the full chain 5x (idempotent) so (dur5 - dur1)/4 = per-chain cost,
// separating fixed harness/reset overhead from kernel time.
// ---------------------------------------------------------------------------

__global__ __launch_bounds__(256) void k0_prep(
    const float* __restrict__ node, const float* __restrict__ Wn,
    const float* __restrict__ bn,   const float* __restrict__ We,
    const float* __restrict__ be,   const float* __restrict__ Wt,
    const float* __restrict__ bt,   float* __restrict__ ws) {
  const int tid = threadIdx.x;
  if (blockIdx.x == 32) {
    for (int idx = tid; idx < 24*128; idx += 256) {
      int t = idx >> 7, d = idx & 127;
      int g = t >> 3, s = t & 7;
      float v = 0.f;
#pragma unroll
      for (int u = 0; u < 8; ++u) v += We[d*8+u] * Wt[((3+g)*8+u)*8 + s];
      ws[OFF_WEFF + t*128 + d] = v;
    }
    if (tid < 24) {
      int g = tid >> 3, s = tid & 7;
      float v = 0.f;
#pragma unroll
      for (int u = 0; u < 8; ++u) v += be[u] * Wt[((3+g)*8+u)*8 + s];
      if (g == 2) v += bt[s];
      ws[OFF_CALL + tid] = v;
    }
  } else {
    __shared__ float ww[24*130];
    __shared__ float nl[12*130];
    for (int idx = tid; idx < 3*128*8; idx += 256) {
      int g = idx >> 10, rem = idx & 1023;
      int d = rem >> 3, s = rem & 7;
      float v = 0.f;
#pragma unroll
      for (int u = 0; u < 8; ++u) v += Wn[d*8+u] * Wt[(g*8+u)*8 + s];
      ww[(g*8+s)*130 + d] = v;
    }
    const int p0 = blockIdx.x * 12;
    for (int f = tid; f < 12*128; f += 256) {
      int pr = f >> 7, d = f & 127;
      nl[pr*130 + d] = node[(p0+pr)*DIM_ + d];
    }
    __syncthreads();
    for (int idx = tid; idx < 12*24; idx += 256) {
      int pr = idx / 24, t = idx - pr*24;
      int g = t >> 3, s = t & 7;
      float v = 0.f;
#pragma unroll
      for (int u = 0; u < 8; ++u) v += bn[u] * Wt[(g*8+u)*8 + s];
      const float* a = nl + pr*130;
      const float* w = ww + (g*8+s)*130;
#pragma unroll 8
      for (int d = 0; d < 128; ++d) v += a[d] * w[d];
      ws[OFF_TN + (p0+pr)*24 + t] = v;
    }
  }
}

__global__ __launch_bounds__(256) void k1_proj(
    const float* __restrict__ P, const float* __restrict__ wsc,
    float* __restrict__ ws) {
  __shared__ float lp[64*132];
  __shared__ float tnl[96*24];
  __shared__ float wl[24*128];
  const int tid = threadIdx.x;
  const int blk = blockIdx.x;
  const int b   = blk / 144;
  const int p0  = (blk - b*144) * 64;
  const float4* Pg = (const float4*)(P + ((size_t)b*PB + p0) * DIM_);
#pragma unroll
  for (int k = 0; k < 8; ++k) {
    int f = tid + k*256;
    float4 v = Pg[f];
    int l = f >> 5, dd = f & 31;
    *(float4*)(lp + l*132 + dd*4) = v;
  }
  const float4* Wg4 = (const float4*)(wsc + OFF_WEFF);
#pragma unroll
  for (int k = 0; k < 3; ++k) ((float4*)wl)[tid + k*256] = Wg4[tid + k*256];
  const float4* Tg4 = (const float4*)(wsc + OFF_TN + b*(96*24));
  for (int f = tid; f < 576; f += 256) ((float4*)tnl)[f] = Tg4[f];
  __syncthreads();

  const int w    = __builtin_amdgcn_readfirstlane((int)(threadIdx.x >> 6));
  const int lane = tid & 63;
  const int t0   = w * 6;
  const int pos  = p0 + lane;
  const int r    = pos / 96;
  const int c    = pos - r*96;
  const float* pa = lp + lane*132;
  const float* wp = wl + t0*128;
  float acc[6] = {0.f,0.f,0.f,0.f,0.f,0.f};
#pragma unroll 4
  for (int d = 0; d < 128; d += 4) {
    float4 va = *(const float4*)(pa + d);
#pragma unroll
    for (int tt = 0; tt < 6; ++tt) {
      float4 wv = *(const float4*)(wp + tt*128 + d);
      acc[tt] += va.x*wv.x + va.y*wv.y + va.z*wv.z + va.w*wv.w;
    }
  }
  float* Xs = ws + OFF_X; float* Ys = ws + OFF_Y; float* Zs = ws + OFF_Z;
#pragma unroll
  for (int tt = 0; tt < 6; ++tt) {
    int t = t0 + tt;
    float val = acc[tt] + wsc[OFF_CALL + t];
    if (t < 8) {
      val += tnl[c*24 + 16 + t];
      Xs[((b*8+t)*N_ + r)*N_ + c] = val;
    } else if (t < 16) {
      int s = t - 8;
      Ys[((b*8+s)*N_ + c)*N_ + r] = val;
    } else {
      int s = t - 16;
      val += tnl[r*24 + s] + tnl[c*24 + 8 + s];
      Zs[((b*8+s)*N_ + r)*N_ + c] = val;
    }
  }
}

__global__ __launch_bounds__(256) void k2_maxplus(
    const float* __restrict__ wsc, float* __restrict__ ws) {
  __shared__ float xs [24*100];
  __shared__ float ysl[24*100];
  __shared__ float zl [24*24];
  __shared__ float red[3*64*9];
  const int tid = threadIdx.x;
  const int bs = blockIdx.x >> 4;
  const int it = (blockIdx.x >> 2) & 3;
  const int jt = blockIdx.x & 3;
  const float* Xg = wsc + OFF_X + (bs*N_ + it*24)*N_;
  const float* Yg = wsc + OFF_Y + (bs*N_ + jt*24)*N_;
  const float* Zg = wsc + OFF_Z + (bs*N_ + it*24)*N_ + jt*24;
  for (int f = tid; f < 576; f += 256) {
    int row = f / 24, kk = f - row*24;
    *(float4*)(xs  + row*100 + kk*4) = *(const float4*)(Xg + row*N_ + kk*4);
    *(float4*)(ysl + row*100 + kk*4) = *(const float4*)(Yg + row*N_ + kk*4);
  }
  for (int f = tid; f < 144; f += 256) {
    int row = f / 6, kk = f - row*6;
    *(float4*)(zl + row*24 + kk*4) = *(const float4*)(Zg + row*N_ + kk*4);
  }
  __syncthreads();
  const int kc = tid >> 6, lane = tid & 63;
  const int ig = lane >> 3, jg = lane & 7;
  float z[3][3], m[3][3];
#pragma unroll
  for (int di = 0; di < 3; ++di)
#pragma unroll
    for (int dj = 0; dj < 3; ++dj) {
      z[di][dj] = zl[(ig*3+di)*24 + jg*3 + dj];
      m[di][dj] = 0.f;
    }
  const float* xb = xs  + (ig*3)*100 + kc*24;
  const float* yb = ysl + (jg*3)*100 + kc*24;
#pragma unroll 4
  for (int k = 0; k < 24; k += 2) {
    float2 xv[3], yv[3];
#pragma unroll
    for (int d = 0; d < 3; ++d) xv[d] = *(const float2*)(xb + d*100 + k);
#pragma unroll
    for (int d = 0; d < 3; ++d) yv[d] = *(const float2*)(yb + d*100 + k);
#pragma unroll
    for (int di = 0; di < 3; ++di)
#pragma unroll
      for (int dj = 0; dj < 3; ++dj) {
        float v0 = xv[di].x + yv[dj].x + z[di][dj];
        float v1 = xv[di].y + yv[dj].y + z[di][dj];
        m[di][dj] = fmaxf(m[di][dj], fmaxf(v0, 0.f));
        m[di][dj] = fmaxf(m[di][dj], fmaxf(v1, 0.f));
      }
  }
  if (kc > 0) {
    float* rp = red + ((kc-1)*64 + lane)*9;
#pragma unroll
    for (int q = 0; q < 9; ++q) rp[q] = m[q/3][q%3];
  }
  __syncthreads();
  if (kc == 0) {
#pragma unroll
    for (int kk = 0; kk < 3; ++kk) {
      const float* rp = red + (kk*64 + lane)*9;
#pragma unroll
      for (int q = 0; q < 9; ++q) m[q/3][q%3] = fmaxf(m[q/3][q%3], rp[q]);
    }
    float* Tg = ws + OFF_T + (bs*N_ + it*24 + ig*3)*N_ + jt*24 + jg*3;
#pragma unroll
    for (int di = 0; di < 3; ++di)
#pragma unroll
      for (int dj = 0; dj < 3; ++dj)
        Tg[di*N_ + dj] = m[di][dj];
  }
}

__global__ __launch_bounds__(256) void k3_out(
    const float* __restrict__ wsc, const float* __restrict__ Wo,
    const float* __restrict__ bo,  float* __restrict__ out) {
  __shared__ float ts[8*72];
  const int tid = threadIdx.x;
  const int blk = blockIdx.x;
  const int b   = blk >> 7;
  const int off = (blk & 127) * 72;
  const float* Tg = wsc + OFF_T + b*8*PB + off;
  for (int f = tid; f < 144; f += 256) {
    int s = f / 18, kk = f - s*18;
    *(float4*)(ts + s*72 + kk*4) = *(const float4*)(Tg + s*PB + kk*4);
  }
  __syncthreads();
  const int dq = tid & 31;
  const int q  = tid >> 5;
  float wo[8][4];
#pragma unroll
  for (int s = 0; s < 8; ++s) {
    float4 wv = *(const float4*)(Wo + s*DIM_ + dq*4);
    wo[s][0]=wv.x; wo[s][1]=wv.y; wo[s][2]=wv.z; wo[s][3]=wv.w;
  }
  float4 bv = *(const float4*)(bo + dq*4);
  const size_t pbase = (size_t)b*PB + off;
  for (int p = 0; p < 9; ++p) {
    int pp = q*9 + p;
    float a0 = bv.x, a1 = bv.y, a2 = bv.z, a3 = bv.w;
#pragma unroll
    for (int s = 0; s < 8; ++s) {
      float tv = ts[s*72 + pp];
      a0 += tv*wo[s][0]; a1 += tv*wo[s][1];
      a2 += tv*wo[s][2]; a3 += tv*wo[s][3];
    }
    float4 o = make_float4(fmaxf(a0,0.f), fmaxf(a1,0.f),
                           fmaxf(a2,0.f), fmaxf(a3,0.f));
    *(float4*)(out + (pbase + pp)*DIM_ + dq*4) = o;
  }
}

extern "C" void kernel_launch(void* const* d_in, const int* in_sizes, int n_in,
                              void* d_out, int out_size, void* d_ws, size_t ws_size,
                              hipStream_t stream) {
  const float* node = (const float*)d_in[0];
  const float* path = (const float*)d_in[1];
  const float* Wn   = (const float*)d_in[2];
  const float* bn   = (const float*)d_in[3];
  const float* We   = (const float*)d_in[4];
  const float* be   = (const float*)d_in[5];
  const float* Wt   = (const float*)d_in[6];
  const float* bt   = (const float*)d_in[7];
  const float* Wo   = (const float*)d_in[8];
  const float* bo   = (const float*)d_in[9];
  float* ws  = (float*)d_ws;
  float* out = (float*)d_out;

  // 5x replication of the identical chain (idempotent): per-chain cost =
  // (dur5 - dur1)/4, fixed overhead = dur1 - per-chain cost.
  for (int rep = 0; rep < 5; ++rep) {
    k0_prep   <<<dim3(33),  dim3(256), 0, stream>>>(node, Wn, bn, We, be, Wt, bt, ws);
    k1_proj   <<<dim3(576), dim3(256), 0, stream>>>(path, ws, ws);
    k2_maxplus<<<dim3(512), dim3(256), 0, stream>>>(ws, ws);
    k3_out    <<<dim3(512), dim3(256), 0, stream>>>(ws, Wo, bo, out);
  }
}

// Round 7
// 120.220 us; speedup vs baseline: 2.2431x; 2.2431x over previous
//
#include <hip/hip_runtime.h>

#define B_   4
#define N_   96
#define DIM_ 128
#define PB   (N_*N_)            // 9216 positions per batch
#define NPOS (B_*PB)            // 36864

// workspace layout (float offsets)
#define OFF_WEFF 0              // [24][128]  effective edge weights (t-major)
#define OFF_CALL 3072           // [24]       combined biases (be@W456, +bt for Z)
#define OFF_TN   3104           // [384][24]  node projections ti/tj/tk (+bn terms)
#define OFF_X    12320          // [4][8][96][96]  X[b][s][i][k] = e_ik + tk
#define OFF_Y    307232         // [4][8][96][96]  Y'[b][s][k][j] = e_kj (NATURAL layout)
#define OFF_Z    602144         // [4][8][96][96]  Z[b][s][i][j] = e_ij+ti+tj+bt
#define OFF_T    897056         // [4][8][96][96]  T[b][s][i][j] = max_k relu(...)

// ---------------------------------------------------------------------------
// K0: combined weights + node projection table (unchanged).
// ---------------------------------------------------------------------------
__global__ __launch_bounds__(256) void k0_prep(
    const float* __restrict__ node, const float* __restrict__ Wn,
    const float* __restrict__ bn,   const float* __restrict__ We,
    const float* __restrict__ be,   const float* __restrict__ Wt,
    const float* __restrict__ bt,   float* __restrict__ ws) {
  const int tid = threadIdx.x;
  if (blockIdx.x == 32) {
    for (int idx = tid; idx < 24*128; idx += 256) {
      int t = idx >> 7, d = idx & 127;
      int g = t >> 3, s = t & 7;
      float v = 0.f;
#pragma unroll
      for (int u = 0; u < 8; ++u) v += We[d*8+u] * Wt[((3+g)*8+u)*8 + s];
      ws[OFF_WEFF + t*128 + d] = v;
    }
    if (tid < 24) {
      int g = tid >> 3, s = tid & 7;
      float v = 0.f;
#pragma unroll
      for (int u = 0; u < 8; ++u) v += be[u] * Wt[((3+g)*8+u)*8 + s];
      if (g == 2) v += bt[s];
      ws[OFF_CALL + tid] = v;
    }
  } else {
    __shared__ float ww[24*130];
    __shared__ float nl[12*130];
    for (int idx = tid; idx < 3*128*8; idx += 256) {
      int g = idx >> 10, rem = idx & 1023;
      int d = rem >> 3, s = rem & 7;
      float v = 0.f;
#pragma unroll
      for (int u = 0; u < 8; ++u) v += Wn[d*8+u] * Wt[(g*8+u)*8 + s];
      ww[(g*8+s)*130 + d] = v;
    }
    const int p0 = blockIdx.x * 12;
    for (int f = tid; f < 12*128; f += 256) {
      int pr = f >> 7, d = f & 127;
      nl[pr*130 + d] = node[(p0+pr)*DIM_ + d];
    }
    __syncthreads();
    for (int idx = tid; idx < 12*24; idx += 256) {
      int pr = idx / 24, t = idx - pr*24;
      int g = t >> 3, s = t & 7;
      float v = 0.f;
#pragma unroll
      for (int u = 0; u < 8; ++u) v += bn[u] * Wt[(g*8+u)*8 + s];
      const float* a = nl + pr*130;
      const float* w = ww + (g*8+s)*130;
#pragma unroll 8
      for (int d = 0; d < 128; ++d) v += a[d] * w[d];
      ws[OFF_TN + (p0+pr)*24 + t] = v;
    }
  }
}

// ---------------------------------------------------------------------------
// K1: project path_emb into X/Y'/Z. ALL stores coalesced: Y stored in its
// natural [b][s][k][j] layout (no 384B-stride scatter / cross-XCD
// partial-line writes). K2 transposes Y at LDS-staging time instead.
// ---------------------------------------------------------------------------
__global__ __launch_bounds__(256) void k1_proj(
    const float* __restrict__ P, const float* __restrict__ wsc,
    float* __restrict__ ws) {
  __shared__ float lp[64*132];
  __shared__ float tnl[96*24];
  __shared__ float wl[24*128];
  const int tid = threadIdx.x;
  const int blk = blockIdx.x;
  const int b   = blk / 144;
  const int p0  = (blk - b*144) * 64;
  const float4* Pg = (const float4*)(P + ((size_t)b*PB + p0) * DIM_);
#pragma unroll
  for (int k = 0; k < 8; ++k) {
    int f = tid + k*256;
    float4 v = Pg[f];
    int l = f >> 5, dd = f & 31;
    *(float4*)(lp + l*132 + dd*4) = v;
  }
  const float4* Wg4 = (const float4*)(wsc + OFF_WEFF);
#pragma unroll
  for (int k = 0; k < 3; ++k) ((float4*)wl)[tid + k*256] = Wg4[tid + k*256];
  const float4* Tg4 = (const float4*)(wsc + OFF_TN + b*(96*24));
  for (int f = tid; f < 576; f += 256) ((float4*)tnl)[f] = Tg4[f];
  __syncthreads();

  const int w    = __builtin_amdgcn_readfirstlane((int)(threadIdx.x >> 6));
  const int lane = tid & 63;
  const int t0   = w * 6;
  const int pos  = p0 + lane;
  const int r    = pos / 96;
  const int c    = pos - r*96;
  const float* pa = lp + lane*132;
  const float* wp = wl + t0*128;
  float acc[6] = {0.f,0.f,0.f,0.f,0.f,0.f};
#pragma unroll 4
  for (int d = 0; d < 128; d += 4) {
    float4 va = *(const float4*)(pa + d);
#pragma unroll
    for (int tt = 0; tt < 6; ++tt) {
      float4 wv = *(const float4*)(wp + tt*128 + d);
      acc[tt] += va.x*wv.x + va.y*wv.y + va.z*wv.z + va.w*wv.w;
    }
  }
  float* Xs = ws + OFF_X; float* Ys = ws + OFF_Y; float* Zs = ws + OFF_Z;
#pragma unroll
  for (int tt = 0; tt < 6; ++tt) {
    int t = t0 + tt;
    float val = acc[tt] + wsc[OFF_CALL + t];
    if (t < 8) {                       // X[b][s=t][i=r][k=c] = e_ik + tk(c)
      val += tnl[c*24 + 16 + t];
      Xs[((b*8+t)*N_ + r)*N_ + c] = val;
    } else if (t < 16) {               // Y'[b][s][k=r][j=c] = e_kj, natural
      int s = t - 8;
      Ys[((b*8+s)*N_ + r)*N_ + c] = val;   // coalesced (c-contiguous)
    } else {                           // Z[b][s][i=r][j=c] = e_ij+ti+tj+bt
      int s = t - 16;
      val += tnl[r*24 + s] + tnl[c*24 + 8 + s];
      Zs[((b*8+s)*N_ + r)*N_ + c] = val;
    }
  }
}

// ---------------------------------------------------------------------------
// K2: T[b,s,i,j] = max_k relu(X[b,s,i,k] + Y'[b,s,k,j] + Z[b,s,i,j])
// Y' is read [k][j-tile] and transposed into ysl[j][k] during LDS staging;
// hot max-plus loop unchanged.
// ---------------------------------------------------------------------------
__global__ __launch_bounds__(256) void k2_maxplus(
    const float* __restrict__ wsc, float* __restrict__ ws) {
  __shared__ float xs [24*100];
  __shared__ float ysl[24*100];
  __shared__ float zl [24*24];
  __shared__ float red[3*64*9];
  const int tid = threadIdx.x;
  const int bs = blockIdx.x >> 4;
  const int it = (blockIdx.x >> 2) & 3;
  const int jt = blockIdx.x & 3;
  const float* Xg = wsc + OFF_X + (bs*N_ + it*24)*N_;
  const float* Yg = wsc + OFF_Y + (size_t)bs*N_*N_ + jt*24;   // [k][j] base
  const float* Zg = wsc + OFF_Z + (bs*N_ + it*24)*N_ + jt*24;
  for (int f = tid; f < 576; f += 256) {
    int row = f / 24, kk = f - row*24;
    *(float4*)(xs + row*100 + kk*4) = *(const float4*)(Xg + row*N_ + kk*4);
  }
  for (int f = tid; f < 576; f += 256) {       // transpose Y'[k][j] -> ysl[j][k]
    int k = f / 6, jq = f - k*6;
    float4 v = *(const float4*)(Yg + k*N_ + jq*4);
    ysl[(jq*4+0)*100 + k] = v.x;
    ysl[(jq*4+1)*100 + k] = v.y;
    ysl[(jq*4+2)*100 + k] = v.z;
    ysl[(jq*4+3)*100 + k] = v.w;
  }
  for (int f = tid; f < 144; f += 256) {
    int row = f / 6, kk = f - row*6;
    *(float4*)(zl + row*24 + kk*4) = *(const float4*)(Zg + row*N_ + kk*4);
  }
  __syncthreads();
  const int kc = tid >> 6, lane = tid & 63;
  const int ig = lane >> 3, jg = lane & 7;
  float z[3][3], m[3][3];
#pragma unroll
  for (int di = 0; di < 3; ++di)
#pragma unroll
    for (int dj = 0; dj < 3; ++dj) {
      z[di][dj] = zl[(ig*3+di)*24 + jg*3 + dj];
      m[di][dj] = 0.f;
    }
  const float* xb = xs  + (ig*3)*100 + kc*24;
  const float* yb = ysl + (jg*3)*100 + kc*24;
#pragma unroll 4
  for (int k = 0; k < 24; k += 2) {
    float2 xv[3], yv[3];
#pragma unroll
    for (int d = 0; d < 3; ++d) xv[d] = *(const float2*)(xb + d*100 + k);
#pragma unroll
    for (int d = 0; d < 3; ++d) yv[d] = *(const float2*)(yb + d*100 + k);
#pragma unroll
    for (int di = 0; di < 3; ++di)
#pragma unroll
      for (int dj = 0; dj < 3; ++dj) {
        float v0 = xv[di].x + yv[dj].x + z[di][dj];
        float v1 = xv[di].y + yv[dj].y + z[di][dj];
        m[di][dj] = fmaxf(m[di][dj], fmaxf(v0, 0.f));
        m[di][dj] = fmaxf(m[di][dj], fmaxf(v1, 0.f));
      }
  }
  if (kc > 0) {
    float* rp = red + ((kc-1)*64 + lane)*9;
#pragma unroll
    for (int q = 0; q < 9; ++q) rp[q] = m[q/3][q%3];
  }
  __syncthreads();
  if (kc == 0) {
#pragma unroll
    for (int kk = 0; kk < 3; ++kk) {
      const float* rp = red + (kk*64 + lane)*9;
#pragma unroll
      for (int q = 0; q < 9; ++q) m[q/3][q%3] = fmaxf(m[q/3][q%3], rp[q]);
    }
    float* Tg = ws + OFF_T + (bs*N_ + it*24 + ig*3)*N_ + jt*24 + jg*3;
#pragma unroll
    for (int di = 0; di < 3; ++di)
#pragma unroll
      for (int dj = 0; dj < 3; ++dj)
        Tg[di*N_ + dj] = m[di][dj];
  }
}

// ---------------------------------------------------------------------------
// K3: out[b,i,j,:] = relu(T[b,:,i,j] @ Wo + bo). (unchanged)
// ---------------------------------------------------------------------------
__global__ __launch_bounds__(256) void k3_out(
    const float* __restrict__ wsc, const float* __restrict__ Wo,
    const float* __restrict__ bo,  float* __restrict__ out) {
  __shared__ float ts[8*72];
  const int tid = threadIdx.x;
  const int blk = blockIdx.x;
  const int b   = blk >> 7;
  const int off = (blk & 127) * 72;
  const float* Tg = wsc + OFF_T + b*8*PB + off;
  for (int f = tid; f < 144; f += 256) {
    int s = f / 18, kk = f - s*18;
    *(float4*)(ts + s*72 + kk*4) = *(const float4*)(Tg + s*PB + kk*4);
  }
  __syncthreads();
  const int dq = tid & 31;
  const int q  = tid >> 5;
  float wo[8][4];
#pragma unroll
  for (int s = 0; s < 8; ++s) {
    float4 wv = *(const float4*)(Wo + s*DIM_ + dq*4);
    wo[s][0]=wv.x; wo[s][1]=wv.y; wo[s][2]=wv.z; wo[s][3]=wv.w;
  }
  float4 bv = *(const float4*)(bo + dq*4);
  const size_t pbase = (size_t)b*PB + off;
  for (int p = 0; p < 9; ++p) {
    int pp = q*9 + p;
    float a0 = bv.x, a1 = bv.y, a2 = bv.z, a3 = bv.w;
#pragma unroll
    for (int s = 0; s < 8; ++s) {
      float tv = ts[s*72 + pp];
      a0 += tv*wo[s][0]; a1 += tv*wo[s][1];
      a2 += tv*wo[s][2]; a3 += tv*wo[s][3];
    }
    float4 o = make_float4(fmaxf(a0,0.f), fmaxf(a1,0.f),
                           fmaxf(a2,0.f), fmaxf(a3,0.f));
    *(float4*)(out + (pbase + pp)*DIM_ + dq*4) = o;
  }
}

extern "C" void kernel_launch(void* const* d_in, const int* in_sizes, int n_in,
                              void* d_out, int out_size, void* d_ws, size_t ws_size,
                              hipStream_t stream) {
  const float* node = (const float*)d_in[0];
  const float* path = (const float*)d_in[1];
  const float* Wn   = (const float*)d_in[2];
  const float* bn   = (const float*)d_in[3];
  const float* We   = (const float*)d_in[4];
  const float* be   = (const float*)d_in[5];
  const float* Wt   = (const float*)d_in[6];
  const float* bt   = (const float*)d_in[7];
  const float* Wo   = (const float*)d_in[8];
  const float* bo   = (const float*)d_in[9];
  float* ws  = (float*)d_ws;
  float* out = (float*)d_out;

  k0_prep   <<<dim3(33),  dim3(256), 0, stream>>>(node, Wn, bn, We, be, Wt, bt, ws);
  k1_proj   <<<dim3(576), dim3(256), 0, stream>>>(path, ws, ws);
  k2_maxplus<<<dim3(512), dim3(256), 0, stream>>>(ws, ws);
  k3_out    <<<dim3(512), dim3(256), 0, stream>>>(ws, Wo, bo, out);
}

// Round 10
// 115.802 us; speedup vs baseline: 2.3287x; 1.0382x over previous
//
#include <hip/hip_runtime.h>

#define B_   4
#define N_   96
#define DIM_ 128
#define PB   (N_*N_)            // 9216 positions per batch
#define NPOS (B_*PB)            // 36864

// workspace layout (float offsets)
#define OFF_WEFF 0              // [24][128]  effective edge weights (t-major)
#define OFF_CALL 3072           // [24]       combined biases (be@W456, +bt for Z)
#define OFF_TN   3104           // [384][24]  node projections ti/tj/tk (+bn terms)
#define OFF_X    12320          // [4][8][96][96]  X[b][s][i][k] = e_ik + tk
#define OFF_Y    307232         // [4][8][96][96]  Y'[b][s][k][j] = e_kj (natural)
#define OFF_Z    602144         // [4][8][96][96]  Z[b][s][i][j] = e_ij+ti+tj+bt
#define OFF_T    897056         // [4][8][96][96]  T[b][s][i][j] = max_k relu(...)

// ---------------------------------------------------------------------------
// K0: combined weights + node projection table (unchanged from round 7).
// ---------------------------------------------------------------------------
__global__ __launch_bounds__(256) void k0_prep(
    const float* __restrict__ node, const float* __restrict__ Wn,
    const float* __restrict__ bn,   const float* __restrict__ We,
    const float* __restrict__ be,   const float* __restrict__ Wt,
    const float* __restrict__ bt,   float* __restrict__ ws) {
  const int tid = threadIdx.x;
  if (blockIdx.x == 32) {
    for (int idx = tid; idx < 24*128; idx += 256) {
      int t = idx >> 7, d = idx & 127;
      int g = t >> 3, s = t & 7;
      float v = 0.f;
#pragma unroll
      for (int u = 0; u < 8; ++u) v += We[d*8+u] * Wt[((3+g)*8+u)*8 + s];
      ws[OFF_WEFF + t*128 + d] = v;
    }
    if (tid < 24) {
      int g = tid >> 3, s = tid & 7;
      float v = 0.f;
#pragma unroll
      for (int u = 0; u < 8; ++u) v += be[u] * Wt[((3+g)*8+u)*8 + s];
      if (g == 2) v += bt[s];
      ws[OFF_CALL + tid] = v;
    }
  } else {
    __shared__ float ww[24*130];
    __shared__ float nl[12*130];
    for (int idx = tid; idx < 3*128*8; idx += 256) {
      int g = idx >> 10, rem = idx & 1023;
      int d = rem >> 3, s = rem & 7;
      float v = 0.f;
#pragma unroll
      for (int u = 0; u < 8; ++u) v += Wn[d*8+u] * Wt[(g*8+u)*8 + s];
      ww[(g*8+s)*130 + d] = v;
    }
    const int p0 = blockIdx.x * 12;
    for (int f = tid; f < 12*128; f += 256) {
      int pr = f >> 7, d = f & 127;
      nl[pr*130 + d] = node[(p0+pr)*DIM_ + d];
    }
    __syncthreads();
    for (int idx = tid; idx < 12*24; idx += 256) {
      int pr = idx / 24, t = idx - pr*24;
      int g = t >> 3, s = t & 7;
      float v = 0.f;
#pragma unroll
      for (int u = 0; u < 8; ++u) v += bn[u] * Wt[(g*8+u)*8 + s];
      const float* a = nl + pr*130;
      const float* w = ww + (g*8+s)*130;
#pragma unroll 8
      for (int d = 0; d < 128; ++d) v += a[d] * w[d];
      ws[OFF_TN + (p0+pr)*24 + t] = v;
    }
  }
}

// ---------------------------------------------------------------------------
// K1: project path_emb into X/Y'/Z.
// Weights read DIRECTLY FROM GLOBAL with wave-uniform addresses (t0 via
// readfirstlane, tt/d compile-time) -> scalar s_load path, zero LDS-pipe
// cost, v_fma uses the SGPR operand. LDS pipe now carries only the 1
// position-read/step (was 7 b128/step = the 13us bottleneck, round-8
// measurement). wl staging dropped -> 43KB LDS -> 3 blocks/CU.
// ---------------------------------------------------------------------------
__global__ __launch_bounds__(256) void k1_proj(
    const float* __restrict__ P, const float* __restrict__ wsc,
    float* __restrict__ ws) {
  __shared__ float lp[64*132];     // 33792 B
  __shared__ float tnl[96*24];     //  9216 B
  const int tid = threadIdx.x;
  const int blk = blockIdx.x;
  const int b   = blk / 144;
  const int p0  = (blk - b*144) * 64;
  const float4* Pg = (const float4*)(P + ((size_t)b*PB + p0) * DIM_);
#pragma unroll
  for (int k = 0; k < 8; ++k) {
    int f = tid + k*256;
    float4 v = Pg[f];
    int l = f >> 5, dd = f & 31;
    *(float4*)(lp + l*132 + dd*4) = v;
  }
  const float4* Tg4 = (const float4*)(wsc + OFF_TN + b*(96*24));
  for (int f = tid; f < 576; f += 256) ((float4*)tnl)[f] = Tg4[f];
  __syncthreads();

  const int w    = __builtin_amdgcn_readfirstlane((int)(threadIdx.x >> 6));
  const int lane = tid & 63;
  const int t0   = w * 6;                      // wave-uniform t-range
  const int pos  = p0 + lane;
  const int r    = pos / 96;
  const int c    = pos - r*96;
  const float* pa = lp + lane*132;
  const float* wp = wsc + OFF_WEFF + t0*128;   // wave-uniform global base
  float acc[6] = {0.f,0.f,0.f,0.f,0.f,0.f};
#pragma unroll 4
  for (int d = 0; d < 128; d += 4) {
    float4 va = *(const float4*)(pa + d);      // per-lane LDS b128 (only LDS op)
#pragma unroll
    for (int tt = 0; tt < 6; ++tt) {
      float4 wv = *(const float4*)(wp + tt*128 + d);  // uniform -> s_load_dwordx4
      acc[tt] += va.x*wv.x + va.y*wv.y + va.z*wv.z + va.w*wv.w;
    }
  }
  float* Xs = ws + OFF_X; float* Ys = ws + OFF_Y; float* Zs = ws + OFF_Z;
#pragma unroll
  for (int tt = 0; tt < 6; ++tt) {
    int t = t0 + tt;
    float val = acc[tt] + wsc[OFF_CALL + t];
    if (t < 8) {                       // X[b][s=t][i=r][k=c] = e_ik + tk(c)
      val += tnl[c*24 + 16 + t];
      Xs[((b*8+t)*N_ + r)*N_ + c] = val;
    } else if (t < 16) {               // Y'[b][s][k=r][j=c] = e_kj, natural
      int s = t - 8;
      Ys[((b*8+s)*N_ + r)*N_ + c] = val;
    } else {                           // Z[b][s][i=r][j=c] = e_ij+ti+tj+bt
      int s = t - 16;
      val += tnl[r*24 + s] + tnl[c*24 + 8 + s];
      Zs[((b*8+s)*N_ + r)*N_ + c] = val;
    }
  }
}

// ---------------------------------------------------------------------------
// K2: T[b,s,i,j] = max_k relu(X[b,s,i,k] + Y'[b,s,k,j] + Z[b,s,i,j])
// (unchanged from round 7)
// ---------------------------------------------------------------------------
__global__ __launch_bounds__(256) void k2_maxplus(
    const float* __restrict__ wsc, float* __restrict__ ws) {
  __shared__ float xs [24*100];
  __shared__ float ysl[24*100];
  __shared__ float zl [24*24];
  __shared__ float red[3*64*9];
  const int tid = threadIdx.x;
  const int bs = blockIdx.x >> 4;
  const int it = (blockIdx.x >> 2) & 3;
  const int jt = blockIdx.x & 3;
  const float* Xg = wsc + OFF_X + (bs*N_ + it*24)*N_;
  const float* Yg = wsc + OFF_Y + (size_t)bs*N_*N_ + jt*24;   // [k][j] base
  const float* Zg = wsc + OFF_Z + (bs*N_ + it*24)*N_ + jt*24;
  for (int f = tid; f < 576; f += 256) {
    int row = f / 24, kk = f - row*24;
    *(float4*)(xs + row*100 + kk*4) = *(const float4*)(Xg + row*N_ + kk*4);
  }
  for (int f = tid; f < 576; f += 256) {       // transpose Y'[k][j] -> ysl[j][k]
    int k = f / 6, jq = f - k*6;
    float4 v = *(const float4*)(Yg + k*N_ + jq*4);
    ysl[(jq*4+0)*100 + k] = v.x;
    ysl[(jq*4+1)*100 + k] = v.y;
    ysl[(jq*4+2)*100 + k] = v.z;
    ysl[(jq*4+3)*100 + k] = v.w;
  }
  for (int f = tid; f < 144; f += 256) {
    int row = f / 6, kk = f - row*6;
    *(float4*)(zl + row*24 + kk*4) = *(const float4*)(Zg + row*N_ + kk*4);
  }
  __syncthreads();
  const int kc = tid >> 6, lane = tid & 63;
  const int ig = lane >> 3, jg = lane & 7;
  float z[3][3], m[3][3];
#pragma unroll
  for (int di = 0; di < 3; ++di)
#pragma unroll
    for (int dj = 0; dj < 3; ++dj) {
      z[di][dj] = zl[(ig*3+di)*24 + jg*3 + dj];
      m[di][dj] = 0.f;
    }
  const float* xb = xs  + (ig*3)*100 + kc*24;
  const float* yb = ysl + (jg*3)*100 + kc*24;
#pragma unroll 4
  for (int k = 0; k < 24; k += 2) {
    float2 xv[3], yv[3];
#pragma unroll
    for (int d = 0; d < 3; ++d) xv[d] = *(const float2*)(xb + d*100 + k);
#pragma unroll
    for (int d = 0; d < 3; ++d) yv[d] = *(const float2*)(yb + d*100 + k);
#pragma unroll
    for (int di = 0; di < 3; ++di)
#pragma unroll
      for (int dj = 0; dj < 3; ++dj) {
        float v0 = xv[di].x + yv[dj].x + z[di][dj];
        float v1 = xv[di].y + yv[dj].y + z[di][dj];
        m[di][dj] = fmaxf(m[di][dj], fmaxf(v0, 0.f));
        m[di][dj] = fmaxf(m[di][dj], fmaxf(v1, 0.f));
      }
  }
  if (kc > 0) {
    float* rp = red + ((kc-1)*64 + lane)*9;
#pragma unroll
    for (int q = 0; q < 9; ++q) rp[q] = m[q/3][q%3];
  }
  __syncthreads();
  if (kc == 0) {
#pragma unroll
    for (int kk = 0; kk < 3; ++kk) {
      const float* rp = red + (kk*64 + lane)*9;
#pragma unroll
      for (int q = 0; q < 9; ++q) m[q/3][q%3] = fmaxf(m[q/3][q%3], rp[q]);
    }
    float* Tg = ws + OFF_T + (bs*N_ + it*24 + ig*3)*N_ + jt*24 + jg*3;
#pragma unroll
    for (int di = 0; di < 3; ++di)
#pragma unroll
      for (int dj = 0; dj < 3; ++dj)
        Tg[di*N_ + dj] = m[di][dj];
  }
}

// ---------------------------------------------------------------------------
// K3: out[b,i,j,:] = relu(T[b,:,i,j] @ Wo + bo). (unchanged from round 7)
// ---------------------------------------------------------------------------
__global__ __launch_bounds__(256) void k3_out(
    const float* __restrict__ wsc, const float* __restrict__ Wo,
    const float* __restrict__ bo,  float* __restrict__ out) {
  __shared__ float ts[8*72];
  const int tid = threadIdx.x;
  const int blk = blockIdx.x;
  const int b   = blk >> 7;
  const int off = (blk & 127) * 72;
  const float* Tg = wsc + OFF_T + b*8*PB + off;
  for (int f = tid; f < 144; f += 256) {
    int s = f / 18, kk = f - s*18;
    *(float4*)(ts + s*72 + kk*4) = *(const float4*)(Tg + s*PB + kk*4);
  }
  __syncthreads();
  const int dq = tid & 31;
  const int q  = tid >> 5;
  float wo[8][4];
#pragma unroll
  for (int s = 0; s < 8; ++s) {
    float4 wv = *(const float4*)(Wo + s*DIM_ + dq*4);
    wo[s][0]=wv.x; wo[s][1]=wv.y; wo[s][2]=wv.z; wo[s][3]=wv.w;
  }
  float4 bv = *(const float4*)(bo + dq*4);
  const size_t pbase = (size_t)b*PB + off;
  for (int p = 0; p < 9; ++p) {
    int pp = q*9 + p;
    float a0 = bv.x, a1 = bv.y, a2 = bv.z, a3 = bv.w;
#pragma unroll
    for (int s = 0; s < 8; ++s) {
      float tv = ts[s*72 + pp];
      a0 += tv*wo[s][0]; a1 += tv*wo[s][1];
      a2 += tv*wo[s][2]; a3 += tv*wo[s][3];
    }
    float4 o = make_float4(fmaxf(a0,0.f), fmaxf(a1,0.f),
                           fmaxf(a2,0.f), fmaxf(a3,0.f));
    *(float4*)(out + (pbase + pp)*DIM_ + dq*4) = o;
  }
}

extern "C" void kernel_launch(void* const* d_in, const int* in_sizes, int n_in,
                              void* d_out, int out_size, void* d_ws, size_t ws_size,
                              hipStream_t stream) {
  const float* node = (const float*)d_in[0];
  const float* path = (const float*)d_in[1];
  const float* Wn   = (const float*)d_in[2];
  const float* bn   = (const float*)d_in[3];
  const float* We   = (const float*)d_in[4];
  const float* be   = (const float*)d_in[5];
  const float* Wt   = (const float*)d_in[6];
  const float* bt   = (const float*)d_in[7];
  const float* Wo   = (const float*)d_in[8];
  const float* bo   = (const float*)d_in[9];
  float* ws  = (float*)d_ws;
  float* out = (float*)d_out;

  k0_prep   <<<dim3(33),  dim3(256), 0, stream>>>(node, Wn, bn, We, be, Wt, bt, ws);
  k1_proj   <<<dim3(576), dim3(256), 0, stream>>>(path, ws, ws);
  k2_maxplus<<<dim3(512), dim3(256), 0, stream>>>(ws, ws);
  k3_out    <<<dim3(512), dim3(256), 0, stream>>>(ws, Wo, bo, out);
}